// Round 1
// baseline (2196.287 us; speedup 1.0000x reference)
//
#include <hip/hip_runtime.h>
#include <math.h>

// GCN: 3x (GEMM -> norm-weighted scatter-agg -> ReLU) -> mean-pool -> head -> softmax
// N=100000 nodes, E=1.6M edges (+N self-loops), nhid=64, 64 graphs, 10 classes.

__global__ void deg_init_kernel(int* __restrict__ deg, int N) {
    int i = blockIdx.x * 256 + threadIdx.x;
    if (i < N) deg[i] = 1;  // self-loop contributes 1 to every node's degree
}

__global__ void deg_count_kernel(const int* __restrict__ dst, int* __restrict__ deg, int E) {
    int e = blockIdx.x * 256 + threadIdx.x;
    if (e < E) atomicAdd(&deg[dst[e]], 1);
}

__global__ void dinv_kernel(const int* __restrict__ deg, float* __restrict__ dinv, int N) {
    int i = blockIdx.x * 256 + threadIdx.x;
    if (i < N) dinv[i] = rsqrtf((float)deg[i]);  // deg >= 1 always (self-loop)
}

// H[N,64] = X[N,FIN] @ W[FIN,64]; 16 rows per block, W + X tile staged in LDS.
template <int FIN>
__global__ __launch_bounds__(256) void gemm_kernel(const float* __restrict__ X,
                                                   const float* __restrict__ W,
                                                   float* __restrict__ H, int N) {
    __shared__ float sW[FIN * 64];
    __shared__ float sX[16 * FIN];
    int tid = threadIdx.x;
    for (int i = tid * 4; i < FIN * 64; i += 1024)
        *(float4*)&sW[i] = *(const float4*)&W[i];
    int rowBase = blockIdx.x * 16;
    for (int i = tid * 4; i < 16 * FIN; i += 1024) {
        int r = i / FIN, c = i - r * FIN;
        int gr = rowBase + r;
        float4 v = make_float4(0.f, 0.f, 0.f, 0.f);
        if (gr < N) v = *(const float4*)&X[(long)gr * FIN + c];
        *(float4*)&sX[i] = v;
    }
    __syncthreads();
    int col = tid & 63, rsub = tid >> 6;
#pragma unroll
    for (int rr = 0; rr < 4; ++rr) {
        int r = rr * 4 + rsub;
        int gr = rowBase + r;
        if (gr < N) {
            float acc = 0.f;
#pragma unroll 16
            for (int k = 0; k < FIN; ++k)
                acc = fmaf(sX[r * FIN + k], sW[k * 64 + col], acc);  // sX broadcast, sW stride-1 (2-way, free)
            H[(long)gr * 64 + col] = acc;
        }
    }
}

// agg[i,c] = b[c] + dinv[i]^2 * h[i,c]   (bias + self-loop term folded in)
__global__ void init_agg_kernel(const float* __restrict__ h, const float* __restrict__ dinv,
                                const float* __restrict__ b, float* __restrict__ agg, int n64) {
    int i = blockIdx.x * 256 + threadIdx.x;
    if (i < n64) {
        int node = i >> 6, c = i & 63;
        float di = dinv[node];
        agg[i] = fmaf(di * di, h[i], b[c]);
    }
}

// One wave per edge, lane = feature column: coalesced 256B gather + 256B atomic scatter.
__global__ __launch_bounds__(256) void scatter_kernel(const int* __restrict__ src,
                                                      const int* __restrict__ dst,
                                                      const float* __restrict__ h,
                                                      const float* __restrict__ dinv,
                                                      float* __restrict__ agg, int E) {
    int gid = blockIdx.x * 256 + threadIdx.x;
    int e = gid >> 6, lane = gid & 63;
    if (e >= E) return;
    int s = src[e], d = dst[e];
    float w = dinv[s] * dinv[d];
    atomicAdd(&agg[(long)d * 64 + lane], w * h[(long)s * 64 + lane]);
}

__global__ void relu_kernel(float* __restrict__ a, int n) {
    int i = blockIdx.x * 256 + threadIdx.x;
    if (i < n) a[i] = fmaxf(a[i], 0.f);
}

__global__ void zero_kernel(float* __restrict__ a, int n) {
    int i = blockIdx.x * 256 + threadIdx.x;
    if (i < n) a[i] = 0.f;
}

// batch is sorted: per-thread running accumulation, flush on graph change (few atomics).
__global__ __launch_bounds__(256) void pool_kernel(const float* __restrict__ h,
                                                   const int* __restrict__ batch,
                                                   float* __restrict__ sums, int N) {
    int col = threadIdx.x & 63, rsub = threadIdx.x >> 6;
    int base = blockIdx.x * 1024;
    float acc = 0.f;
    int curg = -1;
    for (int j = 0; j < 256; ++j) {
        int node = base + j * 4 + rsub;
        if (node >= N) break;
        int g = batch[node];
        if (g != curg) {
            if (curg >= 0) atomicAdd(&sums[curg * 64 + col], acc);
            acc = 0.f;
            curg = g;
        }
        acc += h[(long)node * 64 + col];
    }
    if (curg >= 0) atomicAdd(&sums[curg * 64 + col], acc);
}

__global__ void count_kernel(const int* __restrict__ batch, float* __restrict__ cnts, int N) {
    int i = blockIdx.x * 256 + threadIdx.x;
    if (i < N) atomicAdd(&cnts[batch[i]], 1.0f);
}

// One thread per graph: pooled = sums/cnt, logits = pooled @ Wl + bl, softmax.
__global__ void final_kernel(const float* __restrict__ sums, const float* __restrict__ cnts,
                             const float* __restrict__ Wl, const float* __restrict__ bl,
                             float* __restrict__ out, int G) {
    int g = blockIdx.x * blockDim.x + threadIdx.x;
    if (g >= G) return;
    float inv = 1.0f / fmaxf(cnts[g], 1.0f);
    float logits[10];
#pragma unroll
    for (int k = 0; k < 10; ++k) logits[k] = bl[k];
    for (int c = 0; c < 64; ++c) {
        float p = sums[g * 64 + c] * inv;
#pragma unroll
        for (int k = 0; k < 10; ++k) logits[k] = fmaf(p, Wl[c * 10 + k], logits[k]);
    }
    float m = logits[0];
#pragma unroll
    for (int k = 1; k < 10; ++k) m = fmaxf(m, logits[k]);
    float se = 0.f;
#pragma unroll
    for (int k = 0; k < 10; ++k) {
        logits[k] = expf(logits[k] - m);
        se += logits[k];
    }
    float is = 1.0f / se;
#pragma unroll
    for (int k = 0; k < 10; ++k) out[g * 10 + k] = logits[k] * is;
}

extern "C" void kernel_launch(void* const* d_in, const int* in_sizes, int n_in,
                              void* d_out, int out_size, void* d_ws, size_t ws_size,
                              hipStream_t stream) {
    const float* x    = (const float*)d_in[0];
    const int* edges  = (const int*)d_in[1];
    const int* batch  = (const int*)d_in[2];
    const float* W1   = (const float*)d_in[3];
    const float* b1   = (const float*)d_in[4];
    const float* W2   = (const float*)d_in[5];
    const float* b2   = (const float*)d_in[6];
    const float* W3   = (const float*)d_in[7];
    const float* b3   = (const float*)d_in[8];
    const float* Wl   = (const float*)d_in[9];
    const float* bl   = (const float*)d_in[10];

    const int N = in_sizes[0] / 128;   // 100000
    const int E = in_sizes[1] / 2;     // 1600000
    const int G = out_size / 10;       // 64
    const int* src = edges;
    const int* dst = edges + E;

    float* ws   = (float*)d_ws;
    float* h    = ws;                          // N*64
    float* agg  = ws + (size_t)N * 64;         // N*64
    float* dinv = ws + (size_t)2 * N * 64;     // N
    int*   deg  = (int*)(dinv + N);            // N
    float* sums = (float*)(deg + N);           // G*64
    float* cnts = sums + (size_t)G * 64;       // G  (contiguous with sums)

    const int n64 = N * 64;
    const int gemmGrid = (N + 15) / 16;
    const int scatGrid = (E + 3) / 4;          // 4 waves (edges) per 256-thread block

    // degree + normalization (layer-invariant)
    deg_init_kernel<<<(N + 255) / 256, 256, 0, stream>>>(deg, N);
    deg_count_kernel<<<(E + 255) / 256, 256, 0, stream>>>(dst, deg, E);
    dinv_kernel<<<(N + 255) / 256, 256, 0, stream>>>(deg, dinv, N);

    // layer 1: x[N,128] @ W1 -> h; agg = b1 + dinv^2*h; scatter; relu
    gemm_kernel<128><<<gemmGrid, 256, 0, stream>>>(x, W1, h, N);
    init_agg_kernel<<<(n64 + 255) / 256, 256, 0, stream>>>(h, dinv, b1, agg, n64);
    scatter_kernel<<<scatGrid, 256, 0, stream>>>(src, dst, h, dinv, agg, E);
    relu_kernel<<<(n64 + 255) / 256, 256, 0, stream>>>(agg, n64);

    // layer 2 (GEMM consumes agg fully before init_agg overwrites it — stream-ordered)
    gemm_kernel<64><<<gemmGrid, 256, 0, stream>>>(agg, W2, h, N);
    init_agg_kernel<<<(n64 + 255) / 256, 256, 0, stream>>>(h, dinv, b2, agg, n64);
    scatter_kernel<<<scatGrid, 256, 0, stream>>>(src, dst, h, dinv, agg, E);
    relu_kernel<<<(n64 + 255) / 256, 256, 0, stream>>>(agg, n64);

    // layer 3
    gemm_kernel<64><<<gemmGrid, 256, 0, stream>>>(agg, W3, h, N);
    init_agg_kernel<<<(n64 + 255) / 256, 256, 0, stream>>>(h, dinv, b3, agg, n64);
    scatter_kernel<<<scatGrid, 256, 0, stream>>>(src, dst, h, dinv, agg, E);
    relu_kernel<<<(n64 + 255) / 256, 256, 0, stream>>>(agg, n64);

    // mean-pool per graph + head + softmax
    zero_kernel<<<(G * 65 + 255) / 256, 256, 0, stream>>>(sums, G * 65);  // sums + cnts
    pool_kernel<<<(N + 1023) / 1024, 256, 0, stream>>>(agg, batch, sums, N);
    count_kernel<<<(N + 255) / 256, 256, 0, stream>>>(batch, cnts, N);
    final_kernel<<<1, 64, 0, stream>>>(sums, cnts, Wl, bl, (float*)d_out, G);
}

// Round 2
// 1537.557 us; speedup vs baseline: 1.4284x; 1.4284x over previous
//
#include <hip/hip_runtime.h>
#include <math.h>

// GCN: 3x (GEMM[+fused relu on load] -> norm-weighted scatter-agg) -> mean-pool(+count+relu) -> head -> softmax
// N=100000 nodes, E=1.6M edges (+N self-loops), nhid=64, 64 graphs, 10 classes.

__global__ void deg_init_kernel(int* __restrict__ deg, int N) {
    int i = blockIdx.x * 256 + threadIdx.x;
    if (i < N) deg[i] = 1;  // self-loop contributes 1 to every node's degree
}

__global__ void deg_count_kernel(const int* __restrict__ dst, int* __restrict__ deg, int E) {
    int e = blockIdx.x * 256 + threadIdx.x;
    if (e < E) atomicAdd(&deg[dst[e]], 1);
}

__global__ void dinv_kernel(const int* __restrict__ deg, float* __restrict__ dinv, int N) {
    int i = blockIdx.x * 256 + threadIdx.x;
    if (i < N) dinv[i] = rsqrtf((float)deg[i]);  // deg >= 1 always (self-loop)
}

// H[N,64] = relu?(X)[N,FIN] @ W[FIN,64]; 16 rows per block, W + X tile staged in LDS.
// RELU applies fmaxf(x,0) on the X load (fuses the previous layer's activation).
template <int FIN, bool RELU>
__global__ __launch_bounds__(256) void gemm_kernel(const float* __restrict__ X,
                                                   const float* __restrict__ W,
                                                   float* __restrict__ H, int N) {
    __shared__ float sW[FIN * 64];
    __shared__ float sX[16 * FIN];
    int tid = threadIdx.x;
    for (int i = tid * 4; i < FIN * 64; i += 1024)
        *(float4*)&sW[i] = *(const float4*)&W[i];
    int rowBase = blockIdx.x * 16;
    for (int i = tid * 4; i < 16 * FIN; i += 1024) {
        int r = i / FIN, c = i - r * FIN;
        int gr = rowBase + r;
        float4 v = make_float4(0.f, 0.f, 0.f, 0.f);
        if (gr < N) {
            v = *(const float4*)&X[(long)gr * FIN + c];
            if (RELU) {
                v.x = fmaxf(v.x, 0.f); v.y = fmaxf(v.y, 0.f);
                v.z = fmaxf(v.z, 0.f); v.w = fmaxf(v.w, 0.f);
            }
        }
        *(float4*)&sX[i] = v;
    }
    __syncthreads();
    int col = tid & 63, rsub = tid >> 6;
#pragma unroll
    for (int rr = 0; rr < 4; ++rr) {
        int r = rr * 4 + rsub;
        int gr = rowBase + r;
        if (gr < N) {
            float acc = 0.f;
#pragma unroll 16
            for (int k = 0; k < FIN; ++k)
                acc = fmaf(sX[r * FIN + k], sW[k * 64 + col], acc);  // sX broadcast, sW stride-1 (2-way, free)
            H[(long)gr * 64 + col] = acc;
        }
    }
}

// agg[i,c] = b[c] + dinv[i]^2 * h[i,c]   (bias + self-loop term folded in)
__global__ void init_agg_kernel(const float* __restrict__ h, const float* __restrict__ dinv,
                                const float* __restrict__ b, float* __restrict__ agg, int n64) {
    int i = blockIdx.x * 256 + threadIdx.x;
    if (i < n64) {
        int node = i >> 6, c = i & 63;
        float di = dinv[node];
        agg[i] = fmaf(di * di, h[i], b[c]);
    }
}

// One wave per edge, lane = feature column: coalesced 256B gather + 256B atomic scatter.
__global__ __launch_bounds__(256) void scatter_kernel(const int* __restrict__ src,
                                                      const int* __restrict__ dst,
                                                      const float* __restrict__ h,
                                                      const float* __restrict__ dinv,
                                                      float* __restrict__ agg, int E) {
    int gid = blockIdx.x * 256 + threadIdx.x;
    int e = gid >> 6, lane = gid & 63;
    if (e >= E) return;
    int s = src[e], d = dst[e];
    float w = dinv[s] * dinv[d];
    atomicAdd(&agg[(long)d * 64 + lane], w * h[(long)s * 64 + lane]);
}

__global__ void zero_kernel(float* __restrict__ a, int n) {
    int i = blockIdx.x * 256 + threadIdx.x;
    if (i < n) a[i] = 0.f;
}

// batch is sorted: per-thread running accumulation, flush on graph change (few atomics).
// Also counts nodes per graph (col==0 thread flushes the run length) and applies the
// layer-3 ReLU on load.
__global__ __launch_bounds__(256) void pool_kernel(const float* __restrict__ h,
                                                   const int* __restrict__ batch,
                                                   float* __restrict__ sums,
                                                   float* __restrict__ cnts, int N) {
    int col = threadIdx.x & 63, rsub = threadIdx.x >> 6;
    int base = blockIdx.x * 1024;
    float acc = 0.f, cnt = 0.f;
    int curg = -1;
    for (int j = 0; j < 256; ++j) {
        int node = base + j * 4 + rsub;
        if (node >= N) break;
        int g = batch[node];
        if (g != curg) {
            if (curg >= 0) {
                atomicAdd(&sums[curg * 64 + col], acc);
                if (col == 0) atomicAdd(&cnts[curg], cnt);
            }
            acc = 0.f; cnt = 0.f;
            curg = g;
        }
        acc += fmaxf(h[(long)node * 64 + col], 0.f);  // fused layer-3 ReLU
        cnt += 1.f;
    }
    if (curg >= 0) {
        atomicAdd(&sums[curg * 64 + col], acc);
        if (col == 0) atomicAdd(&cnts[curg], cnt);
    }
}

// One thread per graph: pooled = sums/cnt, logits = pooled @ Wl + bl, softmax.
__global__ void final_kernel(const float* __restrict__ sums, const float* __restrict__ cnts,
                             const float* __restrict__ Wl, const float* __restrict__ bl,
                             float* __restrict__ out, int G) {
    int g = blockIdx.x * blockDim.x + threadIdx.x;
    if (g >= G) return;
    float inv = 1.0f / fmaxf(cnts[g], 1.0f);
    float logits[10];
#pragma unroll
    for (int k = 0; k < 10; ++k) logits[k] = bl[k];
    for (int c = 0; c < 64; ++c) {
        float p = sums[g * 64 + c] * inv;
#pragma unroll
        for (int k = 0; k < 10; ++k) logits[k] = fmaf(p, Wl[c * 10 + k], logits[k]);
    }
    float m = logits[0];
#pragma unroll
    for (int k = 1; k < 10; ++k) m = fmaxf(m, logits[k]);
    float se = 0.f;
#pragma unroll
    for (int k = 0; k < 10; ++k) {
        logits[k] = expf(logits[k] - m);
        se += logits[k];
    }
    float is = 1.0f / se;
#pragma unroll
    for (int k = 0; k < 10; ++k) out[g * 10 + k] = logits[k] * is;
}

extern "C" void kernel_launch(void* const* d_in, const int* in_sizes, int n_in,
                              void* d_out, int out_size, void* d_ws, size_t ws_size,
                              hipStream_t stream) {
    const float* x    = (const float*)d_in[0];
    const int* edges  = (const int*)d_in[1];
    const int* batch  = (const int*)d_in[2];
    const float* W1   = (const float*)d_in[3];
    const float* b1   = (const float*)d_in[4];
    const float* W2   = (const float*)d_in[5];
    const float* b2   = (const float*)d_in[6];
    const float* W3   = (const float*)d_in[7];
    const float* b3   = (const float*)d_in[8];
    const float* Wl   = (const float*)d_in[9];
    const float* bl   = (const float*)d_in[10];

    const int N = in_sizes[0] / 128;   // 100000
    const int E = in_sizes[1] / 2;     // 1600000
    const int G = out_size / 10;       // 64
    const int* src = edges;
    const int* dst = edges + E;

    float* ws   = (float*)d_ws;
    float* h    = ws;                          // N*64
    float* agg  = ws + (size_t)N * 64;         // N*64
    float* dinv = ws + (size_t)2 * N * 64;     // N
    int*   deg  = (int*)(dinv + N);            // N
    float* sums = (float*)(deg + N);           // G*64
    float* cnts = sums + (size_t)G * 64;       // G  (contiguous with sums)

    const int n64 = N * 64;
    const int gemmGrid = (N + 15) / 16;
    const int scatGrid = (E + 3) / 4;          // 4 waves (edges) per 256-thread block

    // degree + normalization (layer-invariant)
    deg_init_kernel<<<(N + 255) / 256, 256, 0, stream>>>(deg, N);
    deg_count_kernel<<<(E + 255) / 256, 256, 0, stream>>>(dst, deg, E);
    dinv_kernel<<<(N + 255) / 256, 256, 0, stream>>>(deg, dinv, N);

    // layer 1: x[N,128] @ W1 -> h; agg = b1 + dinv^2*h; scatter
    gemm_kernel<128, false><<<gemmGrid, 256, 0, stream>>>(x, W1, h, N);
    init_agg_kernel<<<(n64 + 255) / 256, 256, 0, stream>>>(h, dinv, b1, agg, n64);
    scatter_kernel<<<scatGrid, 256, 0, stream>>>(src, dst, h, dinv, agg, E);

    // layer 2 (relu of layer-1 output fused into gemm's X load)
    gemm_kernel<64, true><<<gemmGrid, 256, 0, stream>>>(agg, W2, h, N);
    init_agg_kernel<<<(n64 + 255) / 256, 256, 0, stream>>>(h, dinv, b2, agg, n64);
    scatter_kernel<<<scatGrid, 256, 0, stream>>>(src, dst, h, dinv, agg, E);

    // layer 3
    gemm_kernel<64, true><<<gemmGrid, 256, 0, stream>>>(agg, W3, h, N);
    init_agg_kernel<<<(n64 + 255) / 256, 256, 0, stream>>>(h, dinv, b3, agg, n64);
    scatter_kernel<<<scatGrid, 256, 0, stream>>>(src, dst, h, dinv, agg, E);

    // mean-pool per graph (+count, +fused layer-3 relu) + head + softmax
    zero_kernel<<<(G * 65 + 255) / 256, 256, 0, stream>>>(sums, G * 65);  // sums + cnts
    pool_kernel<<<(N + 1023) / 1024, 256, 0, stream>>>(agg, batch, sums, cnts, N);
    final_kernel<<<1, 64, 0, stream>>>(sums, cnts, Wl, bl, (float*)d_out, G);
}

// Round 3
// 734.732 us; speedup vs baseline: 2.9892x; 2.0927x over previous
//
#include <hip/hip_runtime.h>
#include <math.h>

// GCN via CSR gather: build CSR(dst) once, then 3x (GEMM[+fused relu] -> per-node gather-agg)
// -> mean-pool(+count+relu) -> head -> softmax. No feature atomics.
// N=100000 nodes, E=1.6M edges (+N self-loops folded into gather init), nhid=64, 64 graphs.

__global__ void deg_init_kernel(int* __restrict__ deg, int N) {
    int i = blockIdx.x * 256 + threadIdx.x;
    if (i < N) deg[i] = 1;  // self-loop contributes 1 to every node's degree
}

__global__ void deg_count_kernel(const int* __restrict__ dst, int* __restrict__ deg, int E) {
    int e = blockIdx.x * 256 + threadIdx.x;
    if (e < E) atomicAdd(&deg[dst[e]], 1);
}

__global__ void dinv_kernel(const int* __restrict__ deg, float* __restrict__ dinv, int N) {
    int i = blockIdx.x * 256 + threadIdx.x;
    if (i < N) dinv[i] = rsqrtf((float)deg[i]);  // deg >= 1 always (self-loop)
}

// ---- CSR build: counting sort of edges by dst ----
// cdeg[i] = deg[i]-1 (real in-edges). rowptr = exclusive scan(cdeg).

__global__ void block_sum_kernel(const int* __restrict__ deg, int* __restrict__ bsum, int N) {
    int i = blockIdx.x * 256 + threadIdx.x;
    int v = (i < N) ? deg[i] - 1 : 0;
    for (int off = 32; off; off >>= 1) v += __shfl_down(v, off, 64);
    __shared__ int s[4];
    if ((threadIdx.x & 63) == 0) s[threadIdx.x >> 6] = v;
    __syncthreads();
    if (threadIdx.x == 0) bsum[blockIdx.x] = s[0] + s[1] + s[2] + s[3];
}

// single block: exclusive scan of bsum[nb], nb <= 512
__global__ void scan_bsum_kernel(int* __restrict__ bsum, int nb) {
    __shared__ int s[512];
    int t = threadIdx.x;
    s[t] = (t < nb) ? bsum[t] : 0;
    __syncthreads();
    for (int off = 1; off < 512; off <<= 1) {
        int v = (t >= off) ? s[t - off] : 0;
        __syncthreads();
        s[t] += v;
        __syncthreads();
    }
    if (t < nb) bsum[t] = (t == 0) ? 0 : s[t - 1];
}

__global__ void rowptr_kernel(const int* __restrict__ deg, const int* __restrict__ bsum,
                              int* __restrict__ rowptr, int* __restrict__ cursor, int N) {
    __shared__ int s[256];
    int t = threadIdx.x;
    int i = blockIdx.x * 256 + t;
    int v = (i < N) ? deg[i] - 1 : 0;
    s[t] = v;
    __syncthreads();
    for (int off = 1; off < 256; off <<= 1) {
        int u = (t >= off) ? s[t - off] : 0;
        __syncthreads();
        s[t] += u;
        __syncthreads();
    }
    int excl = s[t] - v + bsum[blockIdx.x];
    if (i < N) { rowptr[i] = excl; cursor[i] = excl; }
    if (i == N - 1) rowptr[N] = excl + v;  // = E
}

// csr[pos] = {src_as_float_bits, w = dinv[src]*dinv[dst]}
__global__ void fill_kernel(const int* __restrict__ src, const int* __restrict__ dst,
                            const float* __restrict__ dinv, int* __restrict__ cursor,
                            float2* __restrict__ csr, int E) {
    int e = blockIdx.x * 256 + threadIdx.x;
    if (e < E) {
        int s = src[e], d = dst[e];
        int pos = atomicAdd(&cursor[d], 1);
        csr[pos] = make_float2(__int_as_float(s), dinv[s] * dinv[d]);
    }
}

// H[N,64] = relu?(X)[N,FIN] @ W[FIN,64]; 16 rows per block, W + X tile staged in LDS.
template <int FIN, bool RELU>
__global__ __launch_bounds__(256) void gemm_kernel(const float* __restrict__ X,
                                                   const float* __restrict__ W,
                                                   float* __restrict__ H, int N) {
    __shared__ float sW[FIN * 64];
    __shared__ float sX[16 * FIN];
    int tid = threadIdx.x;
    for (int i = tid * 4; i < FIN * 64; i += 1024)
        *(float4*)&sW[i] = *(const float4*)&W[i];
    int rowBase = blockIdx.x * 16;
    for (int i = tid * 4; i < 16 * FIN; i += 1024) {
        int r = i / FIN, c = i - r * FIN;
        int gr = rowBase + r;
        float4 v = make_float4(0.f, 0.f, 0.f, 0.f);
        if (gr < N) {
            v = *(const float4*)&X[(long)gr * FIN + c];
            if (RELU) {
                v.x = fmaxf(v.x, 0.f); v.y = fmaxf(v.y, 0.f);
                v.z = fmaxf(v.z, 0.f); v.w = fmaxf(v.w, 0.f);
            }
        }
        *(float4*)&sX[i] = v;
    }
    __syncthreads();
    int col = tid & 63, rsub = tid >> 6;
#pragma unroll
    for (int rr = 0; rr < 4; ++rr) {
        int r = rr * 4 + rsub;
        int gr = rowBase + r;
        if (gr < N) {
            float acc = 0.f;
#pragma unroll 16
            for (int k = 0; k < FIN; ++k)
                acc = fmaf(sX[r * FIN + k], sW[k * 64 + col], acc);
            H[(long)gr * 64 + col] = acc;
        }
    }
}

// One wave per dst node, lane = feature column. acc starts with bias + self-loop term.
// Unroll x4 with independent partials for gather ILP.
__global__ __launch_bounds__(256) void gather_kernel(const float2* __restrict__ csr,
                                                     const int* __restrict__ rowptr,
                                                     const float* __restrict__ h,
                                                     const float* __restrict__ dinv,
                                                     const float* __restrict__ b,
                                                     float* __restrict__ agg, int N) {
    int node = (blockIdx.x * 256 + threadIdx.x) >> 6;
    int lane = threadIdx.x & 63;
    if (node >= N) return;
    int beg = rowptr[node], end = rowptr[node + 1];
    float di = dinv[node];
    float a0 = fmaf(di * di, h[(long)node * 64 + lane], b[lane]);
    float a1 = 0.f, a2 = 0.f, a3 = 0.f;
    int e = beg;
    for (; e + 4 <= end; e += 4) {
        float2 s0 = csr[e], s1 = csr[e + 1], s2 = csr[e + 2], s3 = csr[e + 3];
        a0 = fmaf(s0.y, h[(long)__float_as_int(s0.x) * 64 + lane], a0);
        a1 = fmaf(s1.y, h[(long)__float_as_int(s1.x) * 64 + lane], a1);
        a2 = fmaf(s2.y, h[(long)__float_as_int(s2.x) * 64 + lane], a2);
        a3 = fmaf(s3.y, h[(long)__float_as_int(s3.x) * 64 + lane], a3);
    }
    for (; e < end; ++e) {
        float2 s0 = csr[e];
        a0 = fmaf(s0.y, h[(long)__float_as_int(s0.x) * 64 + lane], a0);
    }
    agg[(long)node * 64 + lane] = (a0 + a1) + (a2 + a3);
}

__global__ void zero_kernel(float* __restrict__ a, int n) {
    int i = blockIdx.x * 256 + threadIdx.x;
    if (i < n) a[i] = 0.f;
}

// batch is sorted: per-thread running accumulation, flush on graph change.
// col==0 thread also flushes run-length counts; fused layer-3 ReLU on load.
__global__ __launch_bounds__(256) void pool_kernel(const float* __restrict__ h,
                                                   const int* __restrict__ batch,
                                                   float* __restrict__ sums,
                                                   float* __restrict__ cnts, int N) {
    int col = threadIdx.x & 63, rsub = threadIdx.x >> 6;
    int base = blockIdx.x * 1024;
    float acc = 0.f, cnt = 0.f;
    int curg = -1;
    for (int j = 0; j < 256; ++j) {
        int node = base + j * 4 + rsub;
        if (node >= N) break;
        int g = batch[node];
        if (g != curg) {
            if (curg >= 0) {
                atomicAdd(&sums[curg * 64 + col], acc);
                if (col == 0) atomicAdd(&cnts[curg], cnt);
            }
            acc = 0.f; cnt = 0.f;
            curg = g;
        }
        acc += fmaxf(h[(long)node * 64 + col], 0.f);
        cnt += 1.f;
    }
    if (curg >= 0) {
        atomicAdd(&sums[curg * 64 + col], acc);
        if (col == 0) atomicAdd(&cnts[curg], cnt);
    }
}

// One thread per graph: pooled = sums/cnt, logits = pooled @ Wl + bl, softmax.
__global__ void final_kernel(const float* __restrict__ sums, const float* __restrict__ cnts,
                             const float* __restrict__ Wl, const float* __restrict__ bl,
                             float* __restrict__ out, int G) {
    int g = blockIdx.x * blockDim.x + threadIdx.x;
    if (g >= G) return;
    float inv = 1.0f / fmaxf(cnts[g], 1.0f);
    float logits[10];
#pragma unroll
    for (int k = 0; k < 10; ++k) logits[k] = bl[k];
    for (int c = 0; c < 64; ++c) {
        float p = sums[g * 64 + c] * inv;
#pragma unroll
        for (int k = 0; k < 10; ++k) logits[k] = fmaf(p, Wl[c * 10 + k], logits[k]);
    }
    float m = logits[0];
#pragma unroll
    for (int k = 1; k < 10; ++k) m = fmaxf(m, logits[k]);
    float se = 0.f;
#pragma unroll
    for (int k = 0; k < 10; ++k) { logits[k] = expf(logits[k] - m); se += logits[k]; }
    float is = 1.0f / se;
#pragma unroll
    for (int k = 0; k < 10; ++k) out[g * 10 + k] = logits[k] * is;
}

extern "C" void kernel_launch(void* const* d_in, const int* in_sizes, int n_in,
                              void* d_out, int out_size, void* d_ws, size_t ws_size,
                              hipStream_t stream) {
    const float* x    = (const float*)d_in[0];
    const int* edges  = (const int*)d_in[1];
    const int* batch  = (const int*)d_in[2];
    const float* W1   = (const float*)d_in[3];
    const float* b1   = (const float*)d_in[4];
    const float* W2   = (const float*)d_in[5];
    const float* b2   = (const float*)d_in[6];
    const float* W3   = (const float*)d_in[7];
    const float* b3   = (const float*)d_in[8];
    const float* Wl   = (const float*)d_in[9];
    const float* bl   = (const float*)d_in[10];

    const int N = in_sizes[0] / 128;   // 100000
    const int E = in_sizes[1] / 2;     // 1600000
    const int G = out_size / 10;       // 64
    const int* src = edges;
    const int* dst = edges + E;

    float* ws     = (float*)d_ws;
    float* h      = ws;                           // N*64
    float* agg    = ws + (size_t)N * 64;          // N*64
    float2* csr   = (float2*)(ws + (size_t)2 * N * 64);  // E float2 (8B-aligned: offset 51.2e6 B)
    float* dinv   = ws + (size_t)2 * N * 64 + (size_t)2 * E;  // N
    int*   deg    = (int*)(dinv + N);             // N
    int*   rowptr = deg + N;                      // N+1
    int*   cursor = rowptr + N + 1;               // N
    int*   bsum   = cursor + N;                   // <=512
    float* sums   = (float*)(bsum + 512);         // G*64
    float* cnts   = sums + (size_t)G * 64;        // G

    const int gemmGrid = (N + 15) / 16;
    const int gatherGrid = (N + 3) / 4;           // 4 waves (nodes) per 256-thread block
    const int nb = (N + 255) / 256;               // 391 <= 512

    // degree + normalization (layer-invariant)
    deg_init_kernel<<<(N + 255) / 256, 256, 0, stream>>>(deg, N);
    deg_count_kernel<<<(E + 255) / 256, 256, 0, stream>>>(dst, deg, E);
    dinv_kernel<<<(N + 255) / 256, 256, 0, stream>>>(deg, dinv, N);

    // CSR build (counting sort by dst), reused by all 3 layers
    block_sum_kernel<<<nb, 256, 0, stream>>>(deg, bsum, N);
    scan_bsum_kernel<<<1, 512, 0, stream>>>(bsum, nb);
    rowptr_kernel<<<nb, 256, 0, stream>>>(deg, bsum, rowptr, cursor, N);
    fill_kernel<<<(E + 255) / 256, 256, 0, stream>>>(src, dst, dinv, cursor, csr, E);

    // layer 1: x[N,128] @ W1 -> h; gather (self-loop + bias folded in)
    gemm_kernel<128, false><<<gemmGrid, 256, 0, stream>>>(x, W1, h, N);
    gather_kernel<<<gatherGrid, 256, 0, stream>>>(csr, rowptr, h, dinv, b1, agg, N);

    // layer 2 (relu of layer-1 output fused into gemm's X load)
    gemm_kernel<64, true><<<gemmGrid, 256, 0, stream>>>(agg, W2, h, N);
    gather_kernel<<<gatherGrid, 256, 0, stream>>>(csr, rowptr, h, dinv, b2, agg, N);

    // layer 3
    gemm_kernel<64, true><<<gemmGrid, 256, 0, stream>>>(agg, W3, h, N);
    gather_kernel<<<gatherGrid, 256, 0, stream>>>(csr, rowptr, h, dinv, b3, agg, N);

    // mean-pool per graph (+count, +fused relu) + head + softmax
    zero_kernel<<<(G * 65 + 255) / 256, 256, 0, stream>>>(sums, G * 65);
    pool_kernel<<<(N + 1023) / 1024, 256, 0, stream>>>(agg, batch, sums, cnts, N);
    final_kernel<<<1, 64, 0, stream>>>(sums, cnts, Wl, bl, (float*)d_out, G);
}

// Round 4
// 665.085 us; speedup vs baseline: 3.3023x; 1.1047x over previous
//
#include <hip/hip_runtime.h>
#include <math.h>

// GCN via CSR gather: build CSR(dst) once, then 3x (GEMM[+fused relu] -> per-node gather-agg)
// -> mean-pool(+count+relu) -> head -> softmax. No feature atomics.
// N=100000 nodes, E=1.6M edges (+N self-loops folded into gather init), nhid=64, 64 graphs.

__global__ void deg_init_kernel(int* __restrict__ deg, int N) {
    int i = blockIdx.x * 256 + threadIdx.x;
    if (i < N) deg[i] = 1;  // self-loop contributes 1 to every node's degree
}

__global__ void deg_count_kernel(const int* __restrict__ dst, int* __restrict__ deg, int E) {
    int e = blockIdx.x * 256 + threadIdx.x;
    if (e < E) atomicAdd(&deg[dst[e]], 1);
}

__global__ void dinv_kernel(const int* __restrict__ deg, float* __restrict__ dinv, int N) {
    int i = blockIdx.x * 256 + threadIdx.x;
    if (i < N) dinv[i] = rsqrtf((float)deg[i]);  // deg >= 1 always (self-loop)
}

// ---- CSR build: counting sort of edges by dst ----
// cdeg[i] = deg[i]-1 (real in-edges). rowptr = exclusive scan(cdeg).

__global__ void block_sum_kernel(const int* __restrict__ deg, int* __restrict__ bsum, int N) {
    int i = blockIdx.x * 256 + threadIdx.x;
    int v = (i < N) ? deg[i] - 1 : 0;
    for (int off = 32; off; off >>= 1) v += __shfl_down(v, off, 64);
    __shared__ int s[4];
    if ((threadIdx.x & 63) == 0) s[threadIdx.x >> 6] = v;
    __syncthreads();
    if (threadIdx.x == 0) bsum[blockIdx.x] = s[0] + s[1] + s[2] + s[3];
}

// single block: exclusive scan of bsum[nb], nb <= 512
__global__ void scan_bsum_kernel(int* __restrict__ bsum, int nb) {
    __shared__ int s[512];
    int t = threadIdx.x;
    s[t] = (t < nb) ? bsum[t] : 0;
    __syncthreads();
    for (int off = 1; off < 512; off <<= 1) {
        int v = (t >= off) ? s[t - off] : 0;
        __syncthreads();
        s[t] += v;
        __syncthreads();
    }
    if (t < nb) bsum[t] = (t == 0) ? 0 : s[t - 1];
}

__global__ void rowptr_kernel(const int* __restrict__ deg, const int* __restrict__ bsum,
                              int* __restrict__ rowptr, int* __restrict__ cursor, int N) {
    __shared__ int s[256];
    int t = threadIdx.x;
    int i = blockIdx.x * 256 + t;
    int v = (i < N) ? deg[i] - 1 : 0;
    s[t] = v;
    __syncthreads();
    for (int off = 1; off < 256; off <<= 1) {
        int u = (t >= off) ? s[t - off] : 0;
        __syncthreads();
        s[t] += u;
        __syncthreads();
    }
    int excl = s[t] - v + bsum[blockIdx.x];
    if (i < N) { rowptr[i] = excl; cursor[i] = excl; }
    if (i == N - 1) rowptr[N] = excl + v;  // = E
}

// csr[pos] = {src_as_float_bits, w = dinv[src]*dinv[dst]}
__global__ void fill_kernel(const int* __restrict__ src, const int* __restrict__ dst,
                            const float* __restrict__ dinv, int* __restrict__ cursor,
                            float2* __restrict__ csr, int E) {
    int e = blockIdx.x * 256 + threadIdx.x;
    if (e < E) {
        int s = src[e], d = dst[e];
        int pos = atomicAdd(&cursor[d], 1);
        csr[pos] = make_float2(__int_as_float(s), dinv[s] * dinv[d]);
    }
}

// H[N,64] = relu?(X)[N,FIN] @ W[FIN,64]; 16 rows per block, W + X tile staged in LDS.
template <int FIN, bool RELU>
__global__ __launch_bounds__(256) void gemm_kernel(const float* __restrict__ X,
                                                   const float* __restrict__ W,
                                                   float* __restrict__ H, int N) {
    __shared__ float sW[FIN * 64];
    __shared__ float sX[16 * FIN];
    int tid = threadIdx.x;
    for (int i = tid * 4; i < FIN * 64; i += 1024)
        *(float4*)&sW[i] = *(const float4*)&W[i];
    int rowBase = blockIdx.x * 16;
    for (int i = tid * 4; i < 16 * FIN; i += 1024) {
        int r = i / FIN, c = i - r * FIN;
        int gr = rowBase + r;
        float4 v = make_float4(0.f, 0.f, 0.f, 0.f);
        if (gr < N) {
            v = *(const float4*)&X[(long)gr * FIN + c];
            if (RELU) {
                v.x = fmaxf(v.x, 0.f); v.y = fmaxf(v.y, 0.f);
                v.z = fmaxf(v.z, 0.f); v.w = fmaxf(v.w, 0.f);
            }
        }
        *(float4*)&sX[i] = v;
    }
    __syncthreads();
    int col = tid & 63, rsub = tid >> 6;
#pragma unroll
    for (int rr = 0; rr < 4; ++rr) {
        int r = rr * 4 + rsub;
        int gr = rowBase + r;
        if (gr < N) {
            float acc = 0.f;
#pragma unroll 16
            for (int k = 0; k < FIN; ++k)
                acc = fmaf(sX[r * FIN + k], sW[k * 64 + col], acc);
            H[(long)gr * 64 + col] = acc;
        }
    }
}

// One wave per dst node, lane = feature column. acc starts with bias + self-loop term.
// Unroll x4 with independent partials for gather ILP.
__global__ __launch_bounds__(256) void gather_kernel(const float2* __restrict__ csr,
                                                     const int* __restrict__ rowptr,
                                                     const float* __restrict__ h,
                                                     const float* __restrict__ dinv,
                                                     const float* __restrict__ b,
                                                     float* __restrict__ agg, int N) {
    int node = (blockIdx.x * 256 + threadIdx.x) >> 6;
    int lane = threadIdx.x & 63;
    if (node >= N) return;
    int beg = rowptr[node], end = rowptr[node + 1];
    float di = dinv[node];
    float a0 = fmaf(di * di, h[(long)node * 64 + lane], b[lane]);
    float a1 = 0.f, a2 = 0.f, a3 = 0.f;
    int e = beg;
    for (; e + 4 <= end; e += 4) {
        float2 s0 = csr[e], s1 = csr[e + 1], s2 = csr[e + 2], s3 = csr[e + 3];
        a0 = fmaf(s0.y, h[(long)__float_as_int(s0.x) * 64 + lane], a0);
        a1 = fmaf(s1.y, h[(long)__float_as_int(s1.x) * 64 + lane], a1);
        a2 = fmaf(s2.y, h[(long)__float_as_int(s2.x) * 64 + lane], a2);
        a3 = fmaf(s3.y, h[(long)__float_as_int(s3.x) * 64 + lane], a3);
    }
    for (; e < end; ++e) {
        float2 s0 = csr[e];
        a0 = fmaf(s0.y, h[(long)__float_as_int(s0.x) * 64 + lane], a0);
    }
    agg[(long)node * 64 + lane] = (a0 + a1) + (a2 + a3);
}

__global__ void zero_kernel(float* __restrict__ a, int n) {
    int i = blockIdx.x * 256 + threadIdx.x;
    if (i < n) a[i] = 0.f;
}

// batch is sorted: one WAVE per 64 contiguous nodes (lane = col), running accumulation
// with flush on graph change. col==0 lane also flushes run-length counts. Fused
// layer-3 ReLU on load. grid = ceil(N/256) blocks of 4 waves -> ~6 waves/CU (was 1.5).
__global__ __launch_bounds__(256) void pool_kernel(const float* __restrict__ h,
                                                   const int* __restrict__ batch,
                                                   float* __restrict__ sums,
                                                   float* __restrict__ cnts, int N) {
    int col = threadIdx.x & 63;
    int wave = threadIdx.x >> 6;
    int base = blockIdx.x * 256 + wave * 64;   // this wave's 64-node span
    float acc = 0.f, cnt = 0.f;
    int curg = -1;
    for (int j = 0; j < 64; ++j) {
        int node = base + j;
        if (node >= N) break;
        int g = batch[node];                    // wave-uniform (scalar load)
        if (g != curg) {
            if (curg >= 0) {
                atomicAdd(&sums[curg * 64 + col], acc);
                if (col == 0) atomicAdd(&cnts[curg], cnt);
            }
            acc = 0.f; cnt = 0.f;
            curg = g;
        }
        acc += fmaxf(h[(long)node * 64 + col], 0.f);
        cnt += 1.f;
    }
    if (curg >= 0) {
        atomicAdd(&sums[curg * 64 + col], acc);
        if (col == 0) atomicAdd(&cnts[curg], cnt);
    }
}

// One thread per graph: pooled = sums/cnt, logits = pooled @ Wl + bl, softmax.
__global__ void final_kernel(const float* __restrict__ sums, const float* __restrict__ cnts,
                             const float* __restrict__ Wl, const float* __restrict__ bl,
                             float* __restrict__ out, int G) {
    int g = blockIdx.x * blockDim.x + threadIdx.x;
    if (g >= G) return;
    float inv = 1.0f / fmaxf(cnts[g], 1.0f);
    float logits[10];
#pragma unroll
    for (int k = 0; k < 10; ++k) logits[k] = bl[k];
    for (int c = 0; c < 64; ++c) {
        float p = sums[g * 64 + c] * inv;
#pragma unroll
        for (int k = 0; k < 10; ++k) logits[k] = fmaf(p, Wl[c * 10 + k], logits[k]);
    }
    float m = logits[0];
#pragma unroll
    for (int k = 1; k < 10; ++k) m = fmaxf(m, logits[k]);
    float se = 0.f;
#pragma unroll
    for (int k = 0; k < 10; ++k) { logits[k] = expf(logits[k] - m); se += logits[k]; }
    float is = 1.0f / se;
#pragma unroll
    for (int k = 0; k < 10; ++k) out[g * 10 + k] = logits[k] * is;
}

extern "C" void kernel_launch(void* const* d_in, const int* in_sizes, int n_in,
                              void* d_out, int out_size, void* d_ws, size_t ws_size,
                              hipStream_t stream) {
    const float* x    = (const float*)d_in[0];
    const int* edges  = (const int*)d_in[1];
    const int* batch  = (const int*)d_in[2];
    const float* W1   = (const float*)d_in[3];
    const float* b1   = (const float*)d_in[4];
    const float* W2   = (const float*)d_in[5];
    const float* b2   = (const float*)d_in[6];
    const float* W3   = (const float*)d_in[7];
    const float* b3   = (const float*)d_in[8];
    const float* Wl   = (const float*)d_in[9];
    const float* bl   = (const float*)d_in[10];

    const int N = in_sizes[0] / 128;   // 100000
    const int E = in_sizes[1] / 2;     // 1600000
    const int G = out_size / 10;       // 64
    const int* src = edges;
    const int* dst = edges + E;

    float* ws     = (float*)d_ws;
    float* h      = ws;                           // N*64
    float* agg    = ws + (size_t)N * 64;          // N*64
    float2* csr   = (float2*)(ws + (size_t)2 * N * 64);  // E float2
    float* dinv   = ws + (size_t)2 * N * 64 + (size_t)2 * E;  // N
    int*   deg    = (int*)(dinv + N);             // N
    int*   rowptr = deg + N;                      // N+1
    int*   cursor = rowptr + N + 1;               // N
    int*   bsum   = cursor + N;                   // <=512
    float* sums   = (float*)(bsum + 512);         // G*64
    float* cnts   = sums + (size_t)G * 64;        // G

    const int gemmGrid = (N + 15) / 16;
    const int gatherGrid = (N + 3) / 4;           // 4 waves (nodes) per 256-thread block
    const int nb = (N + 255) / 256;               // 391 <= 512

    // degree + normalization (layer-invariant)
    deg_init_kernel<<<(N + 255) / 256, 256, 0, stream>>>(deg, N);
    deg_count_kernel<<<(E + 255) / 256, 256, 0, stream>>>(dst, deg, E);
    dinv_kernel<<<(N + 255) / 256, 256, 0, stream>>>(deg, dinv, N);

    // CSR build (counting sort by dst), reused by all 3 layers
    block_sum_kernel<<<nb, 256, 0, stream>>>(deg, bsum, N);
    scan_bsum_kernel<<<1, 512, 0, stream>>>(bsum, nb);
    rowptr_kernel<<<nb, 256, 0, stream>>>(deg, bsum, rowptr, cursor, N);
    fill_kernel<<<(E + 255) / 256, 256, 0, stream>>>(src, dst, dinv, cursor, csr, E);

    // layer 1: x[N,128] @ W1 -> h; gather (self-loop + bias folded in)
    gemm_kernel<128, false><<<gemmGrid, 256, 0, stream>>>(x, W1, h, N);
    gather_kernel<<<gatherGrid, 256, 0, stream>>>(csr, rowptr, h, dinv, b1, agg, N);

    // layer 2 (relu of layer-1 output fused into gemm's X load)
    gemm_kernel<64, true><<<gemmGrid, 256, 0, stream>>>(agg, W2, h, N);
    gather_kernel<<<gatherGrid, 256, 0, stream>>>(csr, rowptr, h, dinv, b2, agg, N);

    // layer 3
    gemm_kernel<64, true><<<gemmGrid, 256, 0, stream>>>(agg, W3, h, N);
    gather_kernel<<<gatherGrid, 256, 0, stream>>>(csr, rowptr, h, dinv, b3, agg, N);

    // mean-pool per graph (+count, +fused relu) + head + softmax
    zero_kernel<<<(G * 65 + 255) / 256, 256, 0, stream>>>(sums, G * 65);
    pool_kernel<<<(N + 255) / 256, 256, 0, stream>>>(agg, batch, sums, cnts, N);
    final_kernel<<<1, 64, 0, stream>>>(sums, cnts, Wl, bl, (float*)d_out, G);
}